// Round 1
// baseline (1794.862 us; speedup 1.0000x reference)
//
#include <hip/hip_runtime.h>
#include <hip/hip_bf16.h>

// Problem constants (from reference)
#define B_     8
#define C_IN   64
#define C_OUT  128
#define HW     256
#define NK     8
#define KS     3

// ---------------------------------------------------------------------------
// Kernel 1: per-(b,c) mean over H*W.  512 blocks x 256 threads.
// ---------------------------------------------------------------------------
__global__ __launch_bounds__(256) void pool_kernel(const float* __restrict__ x,
                                                   float* __restrict__ pooled) {
    const int plane = blockIdx.x;              // b*64 + c
    const float4* p = (const float4*)(x + (size_t)plane * HW * HW);
    float s = 0.f;
    for (int idx = threadIdx.x; idx < (HW * HW) / 4; idx += 256) {
        float4 v = p[idx];
        s += v.x + v.y + v.z + v.w;
    }
    // wave reduce (wave64)
    #pragma unroll
    for (int off = 32; off > 0; off >>= 1) s += __shfl_down(s, off, 64);
    __shared__ float ls[4];
    const int lane = threadIdx.x & 63, wv = threadIdx.x >> 6;
    if (lane == 0) ls[wv] = s;
    __syncthreads();
    if (threadIdx.x == 0) {
        float t = ls[0] + ls[1] + ls[2] + ls[3];
        pooled[plane] = t * (1.0f / (HW * HW));
    }
}

// ---------------------------------------------------------------------------
// Kernel 2: logits = pooled @ attn_w^T + attn_b ; softmax over N.  1 block, 64 thr.
// thread t: b = t/8, n = t%8
// ---------------------------------------------------------------------------
__global__ void attn_kernel(const float* __restrict__ pooled,
                            const float* __restrict__ attn_w,
                            const float* __restrict__ attn_b,
                            float* __restrict__ attn) {
    const int t = threadIdx.x;
    const int b = t >> 3, n = t & 7;
    float s = attn_b[n];
    #pragma unroll 8
    for (int c = 0; c < C_IN; c++) s += pooled[b * C_IN + c] * attn_w[n * C_IN + c];
    __shared__ float logits[B_ * NK];
    logits[t] = s;
    __syncthreads();
    float m = -1e30f;
    #pragma unroll
    for (int j = 0; j < NK; j++) m = fmaxf(m, logits[b * NK + j]);
    float denom = 0.f;
    #pragma unroll
    for (int j = 0; j < NK; j++) denom += expf(logits[b * NK + j] - m);
    attn[t] = expf(s - m) / denom;
}

// ---------------------------------------------------------------------------
// Kernel 3: mixed weights, transposed for conv:
//   Wt[b][i][kh][kw][o] = sum_n attn[b][n] * bank[n][o][i][kh][kw]
// grid = B * 73728 / 256 = 2304 blocks
// ---------------------------------------------------------------------------
__global__ __launch_bounds__(256) void mix_kernel(const float* __restrict__ bank,
                                                  const float* __restrict__ attn,
                                                  float* __restrict__ Wt) {
    const int PER_B = C_OUT * C_IN * KS * KS;   // 73728
    int idx = blockIdx.x * 256 + threadIdx.x;
    int b = idx / PER_B;
    int r = idx % PER_B;                        // flat (o,i,kh,kw) in bank order
    float s = 0.f;
    #pragma unroll
    for (int n = 0; n < NK; n++) s += attn[b * NK + n] * bank[(size_t)n * PER_B + r];
    int kw = r % 3;
    int t1 = r / 3;
    int kh = t1 % 3;
    int t2 = t1 / 3;
    int i = t2 & 63;
    int o = t2 >> 6;
    Wt[((((size_t)b * C_IN + i) * KS + kh) * KS + kw) * C_OUT + o] = s;
}

// ---------------------------------------------------------------------------
// Kernel 4: direct conv, fp32.
// grid = (4 c-blocks, 256 h, 8 b), block = 256 threads.
// Block computes out[b][cblk*32 .. +31][h][0..255].
// Thread (pg = t&31, cg = t>>5): 4 c_out (cg*4) x 8 pixels (pg*8), 32 accumulators.
// Per input channel i: stage 3 input rows (zero-padded, 258 wide) + 9x32 weights
// in LDS, then 3*3*4*8 = 288 FMAs/thread.
// ---------------------------------------------------------------------------
__global__ __launch_bounds__(256) void conv_kernel(const float* __restrict__ x,
                                                   const float* __restrict__ Wt,
                                                   float* __restrict__ out) {
    const int cblk = blockIdx.x;   // 0..3
    const int h    = blockIdx.y;   // 0..255
    const int b    = blockIdx.z;   // 0..7

    __shared__ float sin_[3][264];   // [kh][wp], wp = w+1, borders zero
    __shared__ float swt[9][32];     // [kh*3+kw][c within c-block]

    const int t  = threadIdx.x;
    const int pg = t & 31;
    const int cg = t >> 5;           // 0..7
    const int p0 = pg * 8;

    float acc[4][8];
    #pragma unroll
    for (int ci = 0; ci < 4; ci++)
        #pragma unroll
        for (int j = 0; j < 8; j++) acc[ci][j] = 0.f;

    const float* xb = x + (size_t)b * C_IN * HW * HW;
    const float* wt_base = Wt + (size_t)b * C_IN * 9 * C_OUT + (size_t)cblk * 32;

    for (int i = 0; i < C_IN; i++) {
        __syncthreads();   // protect LDS from previous iteration's readers
        // ---- stage input rows h-1, h, h+1 (zero-padded) ----
        const float* xp = xb + (size_t)i * HW * HW;
        #pragma unroll
        for (int r = 0; r < 3; r++) {
            int hr = h + r - 1;
            float v = 0.f;
            if (hr >= 0 && hr < HW) v = xp[(size_t)hr * HW + t];
            sin_[r][1 + t] = v;
            if (t == 0) {
                sin_[r][0] = 0.f;  sin_[r][257] = 0.f;
                sin_[r][258] = 0.f; sin_[r][259] = 0.f;
            }
        }
        // ---- stage 288 weights (256 threads -> 2 rounds) ----
        {
            int idx = t;                       // 0..255
            swt[idx >> 5][idx & 31] =
                wt_base[((size_t)i * 9 + (idx >> 5)) * C_OUT + (idx & 31)];
            if (t < 32) {
                int idx2 = 256 + t;            // 256..287
                swt[idx2 >> 5][idx2 & 31] =
                    wt_base[((size_t)i * 9 + (idx2 >> 5)) * C_OUT + (idx2 & 31)];
            }
        }
        __syncthreads();

        // ---- compute ----
        #pragma unroll
        for (int kh = 0; kh < 3; kh++) {
            float4 i0 = *(const float4*)&sin_[kh][p0];
            float4 i1 = *(const float4*)&sin_[kh][p0 + 4];
            float4 i2 = *(const float4*)&sin_[kh][p0 + 8];
            float in[10] = {i0.x, i0.y, i0.z, i0.w,
                            i1.x, i1.y, i1.z, i1.w,
                            i2.x, i2.y};
            #pragma unroll
            for (int kw = 0; kw < 3; kw++) {
                float4 wv = *(const float4*)&swt[kh * 3 + kw][cg * 4];
                float wr[4] = {wv.x, wv.y, wv.z, wv.w};
                #pragma unroll
                for (int ci = 0; ci < 4; ci++)
                    #pragma unroll
                    for (int j = 0; j < 8; j++)
                        acc[ci][j] = fmaf(wr[ci], in[j + kw], acc[ci][j]);
            }
        }
    }

    // ---- epilogue: coalesced float4 stores ----
    const int c0 = cblk * 32 + cg * 4;
    #pragma unroll
    for (int ci = 0; ci < 4; ci++) {
        size_t o = (((size_t)b * C_OUT + c0 + ci) * HW + h) * HW + p0;
        *(float4*)&out[o]     = make_float4(acc[ci][0], acc[ci][1], acc[ci][2], acc[ci][3]);
        *(float4*)&out[o + 4] = make_float4(acc[ci][4], acc[ci][5], acc[ci][6], acc[ci][7]);
    }
}

// ---------------------------------------------------------------------------
extern "C" void kernel_launch(void* const* d_in, const int* in_sizes, int n_in,
                              void* d_out, int out_size, void* d_ws, size_t ws_size,
                              hipStream_t stream) {
    const float* x      = (const float*)d_in[0];   // (8,64,256,256)
    const float* bank   = (const float*)d_in[1];   // (8,128,64,3,3)
    const float* attn_w = (const float*)d_in[2];   // (8,64)
    const float* attn_b = (const float*)d_in[3];   // (8,)
    float* out = (float*)d_out;                    // (8,128,256,256)

    float* ws     = (float*)d_ws;
    float* Wt     = ws;                                  // 8*64*9*128 = 589824 floats
    float* pooled = ws + (size_t)B_ * C_IN * 9 * C_OUT;  // 512 floats
    float* attn   = pooled + B_ * C_IN;                  // 64 floats

    pool_kernel<<<B_ * C_IN, 256, 0, stream>>>(x, pooled);
    attn_kernel<<<1, 64, 0, stream>>>(pooled, attn_w, attn_b, attn);
    mix_kernel<<<(B_ * C_OUT * C_IN * KS * KS) / 256, 256, 0, stream>>>(bank, attn, Wt);
    conv_kernel<<<dim3(4, HW, B_), 256, 0, stream>>>(x, Wt, out);
}

// Round 2
// 548.756 us; speedup vs baseline: 3.2708x; 3.2708x over previous
//
#include <hip/hip_runtime.h>
#include <hip/hip_bf16.h>

#define B_     8
#define C_IN   64
#define C_OUT  128
#define HW     256
#define NK     8
#define KS     3

typedef __attribute__((ext_vector_type(8))) short bf16x8;
typedef __attribute__((ext_vector_type(4))) float f32x4;

__device__ inline unsigned short f2bf(float f) {
    union { float f; unsigned int u; } a; a.f = f;
    unsigned int u = a.u;
    u += 0x7fffu + ((u >> 16) & 1u);   // round-to-nearest-even
    return (unsigned short)(u >> 16);
}

// ---------------------------------------------------------------------------
// Kernel 1: per-(b,c) mean over H*W.  512 blocks x 256 threads.
// ---------------------------------------------------------------------------
__global__ __launch_bounds__(256) void pool_kernel(const float* __restrict__ x,
                                                   float* __restrict__ pooled) {
    const int plane = blockIdx.x;              // b*64 + c
    const float4* p = (const float4*)(x + (size_t)plane * HW * HW);
    float s = 0.f;
    for (int idx = threadIdx.x; idx < (HW * HW) / 4; idx += 256) {
        float4 v = p[idx];
        s += v.x + v.y + v.z + v.w;
    }
    #pragma unroll
    for (int off = 32; off > 0; off >>= 1) s += __shfl_down(s, off, 64);
    __shared__ float ls[4];
    const int lane = threadIdx.x & 63, wv = threadIdx.x >> 6;
    if (lane == 0) ls[wv] = s;
    __syncthreads();
    if (threadIdx.x == 0) {
        float t = ls[0] + ls[1] + ls[2] + ls[3];
        pooled[plane] = t * (1.0f / (HW * HW));
    }
}

// ---------------------------------------------------------------------------
// Kernel 2: logits + softmax.  1 block, 64 threads. thread t: b=t/8, n=t%8
// ---------------------------------------------------------------------------
__global__ void attn_kernel(const float* __restrict__ pooled,
                            const float* __restrict__ attn_w,
                            const float* __restrict__ attn_b,
                            float* __restrict__ attn) {
    const int t = threadIdx.x;
    const int b = t >> 3, n = t & 7;
    float s = attn_b[n];
    #pragma unroll 8
    for (int c = 0; c < C_IN; c++) s += pooled[b * C_IN + c] * attn_w[n * C_IN + c];
    __shared__ float logits[B_ * NK];
    logits[t] = s;
    __syncthreads();
    float m = -1e30f;
    #pragma unroll
    for (int j = 0; j < NK; j++) m = fmaxf(m, logits[b * NK + j]);
    float denom = 0.f;
    #pragma unroll
    for (int j = 0; j < NK; j++) denom += expf(logits[b * NK + j] - m);
    attn[t] = expf(s - m) / denom;
}

// ---------------------------------------------------------------------------
// Kernel 3: mixed weights -> bf16, pre-swizzled into MFMA A-fragment order:
//   Wt2[b][kh][kw][ic][o][di]  (ic = i>>5, di = i&31)
// grid = 8*73728/256 = 2304 blocks
// ---------------------------------------------------------------------------
__global__ __launch_bounds__(256) void mix_kernel(const float* __restrict__ bank,
                                                  const float* __restrict__ attn,
                                                  unsigned short* __restrict__ Wt2) {
    const int PER_B = C_OUT * C_IN * KS * KS;   // 73728
    int idx = blockIdx.x * 256 + threadIdx.x;
    int b = idx / PER_B;
    int r = idx % PER_B;                        // flat (o,i,kh,kw) in bank order
    float s = 0.f;
    #pragma unroll
    for (int n = 0; n < NK; n++) s += attn[b * NK + n] * bank[(size_t)n * PER_B + r];
    int kw = r % 3;
    int t1 = r / 3;
    int kh = t1 % 3;
    int t2 = t1 / 3;
    int i = t2 & 63;
    int o = t2 >> 6;
    size_t off = (((size_t)((b * 3 + kh) * 3 + kw) * 2 + (i >> 5)) * 128 + o) * 32 + (i & 31);
    Wt2[off] = f2bf(s);
}

// ---------------------------------------------------------------------------
// Kernel 4: implicit-GEMM conv via mfma_f32_16x16x32_bf16.
// grid = (2 w-blocks, 256 h, 8 b), block = 256 (4 waves, 2x2).
// Block tile: M=128 (all c_out) x N=128 pixels (half row h).
// Per kh: stage padded input row (130 w x 64 ch, bf16, [w][i] stride 72) in LDS,
// then 6 K32-steps (3 kw x 2 i-chunks). A-frags from global (L2-resident Wt2),
// B-frags ds_read_b128 from LDS. Wave tile 64x64 = 4x4 MFMAs per K-step.
// ---------------------------------------------------------------------------
__global__ __launch_bounds__(256) void conv_mfma(const float* __restrict__ x,
                                                 const short* __restrict__ Wt2,
                                                 float* __restrict__ out) {
    const int w0 = blockIdx.x * 128;   // 0 or 128
    const int h  = blockIdx.y;
    const int b  = blockIdx.z;

    const int t    = threadIdx.x;
    const int lane = t & 63;
    const int wid  = t >> 6;
    const int wm   = (wid & 1) * 64;   // wave M offset
    const int wn   = (wid >> 1) * 64;  // wave N offset
    const int l15  = lane & 15;
    const int quad = lane >> 4;

    __shared__ short sxs[130 * 72];    // [w_local][i], i-stride 72 (16B aligned, padded)

    f32x4 acc[4][4];
    #pragma unroll
    for (int mt = 0; mt < 4; mt++)
        #pragma unroll
        for (int nt = 0; nt < 4; nt++)
            acc[mt][nt] = (f32x4){0.f, 0.f, 0.f, 0.f};

    for (int kh = 0; kh < 3; kh++) {
        __syncthreads();   // protect LDS from previous phase's readers
        const int hr = h + kh - 1;
        const bool rv = (hr >= 0) && (hr < HW);
        // ---- stage row hr: wl in [0,128) by all threads, 2 channels each ----
        {
            const int wl = t & 127;
            const int w  = w0 + wl - 1;
            const bool wvalid = rv && (w >= 0) && (w < HW);
            #pragma unroll
            for (int it = 0; it < 16; it++) {
                const int ip = it * 2 + (t >> 7);   // channel-pair index 0..31
                float v0 = 0.f, v1 = 0.f;
                if (wvalid) {
                    const float* px = x + (((size_t)(b * C_IN + 2 * ip) * HW + hr) * HW + w);
                    v0 = px[0];
                    v1 = px[HW * HW];
                }
                ushort2 u;
                u.x = f2bf(v0);
                u.y = f2bf(v1);
                *(ushort2*)&sxs[wl * 72 + 2 * ip] = u;
            }
            // tail: wl = 128, 129
            if (t < 128) {
                const int i2  = t >> 1;
                const int wl2 = 128 + (t & 1);
                const int w2  = w0 + wl2 - 1;
                unsigned short uv = 0;
                if (rv && w2 < HW)
                    uv = f2bf(x[((size_t)(b * C_IN + i2) * HW + hr) * HW + w2]);
                ((unsigned short*)sxs)[wl2 * 72 + i2] = uv;
            }
        }
        __syncthreads();

        // ---- 6 K32-steps ----
        const short* wbase = Wt2 + (size_t)((b * 3 + kh) * 3) * 2 * 4096;
        #pragma unroll
        for (int kw = 0; kw < 3; kw++) {
            #pragma unroll
            for (int ic = 0; ic < 2; ic++) {
                const short* Ap = wbase + (size_t)(kw * 2 + ic) * 4096
                                + (wm + l15) * 32 + quad * 8;
                bf16x8 a0 = *(const bf16x8*)(Ap);
                bf16x8 a1 = *(const bf16x8*)(Ap + 512);
                bf16x8 a2 = *(const bf16x8*)(Ap + 1024);
                bf16x8 a3 = *(const bf16x8*)(Ap + 1536);
                const short* Bp = sxs + (wn + l15 + kw) * 72 + ic * 32 + quad * 8;
                bf16x8 b0 = *(const bf16x8*)(Bp);
                bf16x8 b1 = *(const bf16x8*)(Bp + 16 * 72);
                bf16x8 b2 = *(const bf16x8*)(Bp + 32 * 72);
                bf16x8 b3 = *(const bf16x8*)(Bp + 48 * 72);
                acc[0][0] = __builtin_amdgcn_mfma_f32_16x16x32_bf16(a0, b0, acc[0][0], 0, 0, 0);
                acc[0][1] = __builtin_amdgcn_mfma_f32_16x16x32_bf16(a0, b1, acc[0][1], 0, 0, 0);
                acc[0][2] = __builtin_amdgcn_mfma_f32_16x16x32_bf16(a0, b2, acc[0][2], 0, 0, 0);
                acc[0][3] = __builtin_amdgcn_mfma_f32_16x16x32_bf16(a0, b3, acc[0][3], 0, 0, 0);
                acc[1][0] = __builtin_amdgcn_mfma_f32_16x16x32_bf16(a1, b0, acc[1][0], 0, 0, 0);
                acc[1][1] = __builtin_amdgcn_mfma_f32_16x16x32_bf16(a1, b1, acc[1][1], 0, 0, 0);
                acc[1][2] = __builtin_amdgcn_mfma_f32_16x16x32_bf16(a1, b2, acc[1][2], 0, 0, 0);
                acc[1][3] = __builtin_amdgcn_mfma_f32_16x16x32_bf16(a1, b3, acc[1][3], 0, 0, 0);
                acc[2][0] = __builtin_amdgcn_mfma_f32_16x16x32_bf16(a2, b0, acc[2][0], 0, 0, 0);
                acc[2][1] = __builtin_amdgcn_mfma_f32_16x16x32_bf16(a2, b1, acc[2][1], 0, 0, 0);
                acc[2][2] = __builtin_amdgcn_mfma_f32_16x16x32_bf16(a2, b2, acc[2][2], 0, 0, 0);
                acc[2][3] = __builtin_amdgcn_mfma_f32_16x16x32_bf16(a2, b3, acc[2][3], 0, 0, 0);
                acc[3][0] = __builtin_amdgcn_mfma_f32_16x16x32_bf16(a3, b0, acc[3][0], 0, 0, 0);
                acc[3][1] = __builtin_amdgcn_mfma_f32_16x16x32_bf16(a3, b1, acc[3][1], 0, 0, 0);
                acc[3][2] = __builtin_amdgcn_mfma_f32_16x16x32_bf16(a3, b2, acc[3][2], 0, 0, 0);
                acc[3][3] = __builtin_amdgcn_mfma_f32_16x16x32_bf16(a3, b3, acc[3][3], 0, 0, 0);
            }
        }
    }

    // ---- epilogue: C/D layout col(N)=lane&15, row(M)=quad*4+reg ----
    #pragma unroll
    for (int mt = 0; mt < 4; mt++) {
        const int o = wm + mt * 16 + quad * 4;
        #pragma unroll
        for (int nt = 0; nt < 4; nt++) {
            const int w = w0 + wn + nt * 16 + l15;
            float* op = out + (((size_t)(b * C_OUT + o) * HW + h) * HW + w);
            #pragma unroll
            for (int r = 0; r < 4; r++) op[(size_t)r * HW * HW] = acc[mt][nt][r];
        }
    }
}

// ---------------------------------------------------------------------------
extern "C" void kernel_launch(void* const* d_in, const int* in_sizes, int n_in,
                              void* d_out, int out_size, void* d_ws, size_t ws_size,
                              hipStream_t stream) {
    const float* x      = (const float*)d_in[0];   // (8,64,256,256)
    const float* bank   = (const float*)d_in[1];   // (8,128,64,3,3)
    const float* attn_w = (const float*)d_in[2];   // (8,64)
    const float* attn_b = (const float*)d_in[3];   // (8,)
    float* out = (float*)d_out;                    // (8,128,256,256)

    unsigned short* Wt2 = (unsigned short*)d_ws;                    // 589824 bf16
    float* pooled = (float*)((char*)d_ws + 589824 * sizeof(short)); // 512 floats
    float* attn   = pooled + B_ * C_IN;                             // 64 floats

    pool_kernel<<<B_ * C_IN, 256, 0, stream>>>(x, pooled);
    attn_kernel<<<1, 64, 0, stream>>>(pooled, attn_w, attn_b, attn);
    mix_kernel<<<(B_ * C_OUT * C_IN * KS * KS) / 256, 256, 0, stream>>>(bank, attn, Wt2);
    conv_mfma<<<dim3(2, HW, B_), 256, 0, stream>>>(x, (const short*)Wt2, out);
}